// Round 3
// baseline (26388.025 us; speedup 1.0000x reference)
//
#include <hip/hip_runtime.h>
#include <hip/hip_bf16.h>
#include <math.h>

// Problem constants: T=256, B=64, I=512, H=512
#define T_LEN 256
#define BATCH 64
#define HSZ   512

typedef __bf16 bf16x8 __attribute__((ext_vector_type(8)));
typedef float  f32x4  __attribute__((ext_vector_type(4)));

// ---------- bf16 split helpers ----------
__device__ __forceinline__ unsigned short f2bf_rne(float f) {
    union { float f; unsigned int u; } c; c.f = f;
    unsigned int u = c.u;
    unsigned int r = (u + 0x7fffu + ((u >> 16) & 1u)) >> 16;
    return (unsigned short)r;
}
__device__ __forceinline__ float bf2f(unsigned short h) {
    union { unsigned int u; float f; } c; c.u = ((unsigned int)h) << 16;
    return c.f;
}
__device__ __forceinline__ void split_rne(float v, unsigned short& hi, unsigned short& lo) {
    hi = f2bf_rne(v);
    lo = f2bf_rne(v - bf2f(hi));
}
// fast truncating split (4 VALU): hi = trunc16(v), lo = trunc16(v - hi). |err| <= 2^-16 |v|
__device__ __forceinline__ void split2(float v, unsigned short& hi, unsigned short& lo) {
    unsigned int u = __float_as_uint(v);
    hi = (unsigned short)(u >> 16);
    float rem = v - __uint_as_float(u & 0xffff0000u);
    lo = (unsigned short)(__float_as_uint(rem) >> 16);
}

__device__ __forceinline__ float sigmoid_fast(float x) {
    return 1.0f / (1.0f + __expf(-x));
}
__device__ __forceinline__ float tanh_fast(float x) {
    float e = __expf(2.0f * x);
    return 1.0f - 2.0f / (e + 1.0f);
}

// ---------- init: split h0 into hi/lo state buffers (parity 0) ----------
__global__ void init_split(const float* __restrict__ h0,
                           unsigned short* __restrict__ hhi0, unsigned short* __restrict__ hlo0) {
    int i = blockIdx.x * blockDim.x + threadIdx.x;
    if (i < 4 * BATCH * HSZ) {
        unsigned short h, l;
        split2(h0[i], h, l);
        hhi0[i] = h; hlo0[i] = l;
    }
}

// ---------- weight packing (same layout as round 2, RNE split) ----------
// wp[cell][ft][kc][part][lane*8]; A-frag (16x16x32): lane l holds
// A[pr = ft*16 + (l&15)][k = kc*32 + (l>>4)*8 + e]; pr = u*4 + g.
template<int DIN>
__global__ __launch_bounds__(256)
void pack_weights(const float* __restrict__ wih0, const float* __restrict__ whh0,
                  const float* __restrict__ wih1, const float* __restrict__ whh1,
                  unsigned short* __restrict__ wp) {
    constexpr int KTOT = DIN + 512;
    constexpr int KC = KTOT / 32;
    const size_t cell_sz = (size_t)128 * KC * 2 * 512;
    int t = blockIdx.x * blockDim.x + threadIdx.x;
    int total = 2 * 128 * KC * 64;
    if (t >= total) return;
    int lane = t & 63;
    int kc   = (t >> 6) % KC;
    int ft   = ((t >> 6) / KC) & 127;
    int cell = t / (64 * KC * 128);
    const float* wih = cell ? wih1 : wih0;
    const float* whh = cell ? whh1 : whh0;
    int pr = ft * 16 + (lane & 15);
    int u = pr >> 2, g = pr & 3;
    int row = g * 512 + u;
    int kbase = kc * 32 + (lane >> 4) * 8;
    union { unsigned short s[8]; uint4 v; } H, L;
#pragma unroll
    for (int e = 0; e < 8; ++e) {
        int k = kbase + e;
        float v = (k < DIN) ? wih[(size_t)row * DIN + k]
                            : whh[(size_t)row * 512 + (k - DIN)];
        split_rne(v, H.s[e], L.s[e]);
    }
    size_t base = (size_t)cell * cell_sz + (((size_t)ft * KC + kc) * 2) * 512 + (size_t)lane * 8;
    *reinterpret_cast<uint4*>(&wp[base])       = H.v;
    *reinterpret_cast<uint4*>(&wp[base + 512]) = L.v;
}

// ---------- shared memory union ----------
struct Shm {
    union {
        struct { unsigned short hi[64][520]; unsigned short lo[64][520]; } z; // 133,120 B
        float part[4][4][16][17];                                             // 17,408 B
    };
};

// ---------- two-level grid barrier (device-scope atomics) ----------
// counters padded to 16 uints (64B) each.
__device__ __forceinline__ void barrier2(unsigned* grp, unsigned* root, unsigned* gen,
                                         int gidx, unsigned gsz, unsigned ng) {
    __syncthreads();
    if (threadIdx.x == 0) {
        unsigned g0 = __hip_atomic_load(gen, __ATOMIC_RELAXED, __HIP_MEMORY_SCOPE_AGENT);
        unsigned a = __hip_atomic_fetch_add(grp + (size_t)gidx * 16, 1u,
                                            __ATOMIC_ACQ_REL, __HIP_MEMORY_SCOPE_AGENT);
        bool released = false;
        if (a == gsz - 1u) {
            unsigned r = __hip_atomic_fetch_add(root, 1u, __ATOMIC_ACQ_REL, __HIP_MEMORY_SCOPE_AGENT);
            if (r == ng - 1u) {
                for (unsigned i = 0; i < ng; ++i)
                    __hip_atomic_store(grp + (size_t)i * 16, 0u, __ATOMIC_RELAXED, __HIP_MEMORY_SCOPE_AGENT);
                __hip_atomic_store(root, 0u, __ATOMIC_RELAXED, __HIP_MEMORY_SCOPE_AGENT);
                __hip_atomic_fetch_add(gen, 1u, __ATOMIC_RELEASE, __HIP_MEMORY_SCOPE_AGENT);
                released = true;
            }
        }
        if (!released) {
            while (__hip_atomic_load(gen, __ATOMIC_ACQUIRE, __HIP_MEMORY_SCOPE_AGENT) == g0)
                __builtin_amdgcn_s_sleep(2);
        }
    }
    __syncthreads();
}

// ---------- one layer phase (256 steps, weights in registers) ----------
// Block bx: cd = bx&1 (dir), ftb = bx>>1 (16-row gate strip = 4 units of one cell).
// 4 waves split K 4-ways; wave w = tid>>6, lane l = tid&63.
// Epilogue thread (u_l = tid>>6, b = tid&63) owns h/c regs of (u = ftb*4+u_l, b).
template<int DIN>
__device__ void run_phase(Shm& sm,
    const float* __restrict__ zf32,                 // DIN==512: x (T,B,512)
    const unsigned short* __restrict__ zsh,         // DIN==1024: h1 hi (T,B,1024)
    const unsigned short* __restrict__ zsl,         // DIN==1024: h1 lo
    const unsigned short* __restrict__ wp,          // layer packed weights (2 cells)
    const float* __restrict__ bihf, const float* __restrict__ bhhf,
    const float* __restrict__ bihb, const float* __restrict__ bhhb,
    const float* __restrict__ h0, const float* __restrict__ c0,
    unsigned short* __restrict__ hhi0, unsigned short* __restrict__ hlo0,
    unsigned short* __restrict__ hhi1, unsigned short* __restrict__ hlo1,
    unsigned short* __restrict__ oshi, unsigned short* __restrict__ oslo, // layer0 out (h1 split)
    float* __restrict__ of32,                       // layer1 out (d_out)
    const int* __restrict__ lengths,
    unsigned* bar, int cellbase)
{
    constexpr int KTOT = DIN + 512;
    constexpr int KC   = KTOT / 32;
    constexpr int NCH  = KTOT / 512;

    const int bx  = blockIdx.x;
    const int cd  = bx & 1;
    const int ftb = bx >> 1;
    const int cell = cellbase + cd;
    const int tid = threadIdx.x;
    const int w = tid >> 6, l = tid & 63;

    unsigned* cgrp  = bar + (size_t)cd * 96;
    unsigned* croot = bar + (size_t)cd * 96 + 64;
    unsigned* cgen  = bar + (size_t)cd * 96 + 80;
    const int gidx = ftb >> 5;   // 4 groups of 32 blocks per cell

    // ---- load persistent weight fragments into registers ----
    bf16x8 whi[NCH * 4], wlo[NCH * 4];
    const unsigned short* wpc = wp + (size_t)cd * ((size_t)128 * KC * 2 * 512);
#pragma unroll
    for (int ch = 0; ch < NCH; ++ch) {
#pragma unroll
        for (int j = 0; j < 4; ++j) {
            int kc = ch * 16 + w * 4 + j;
            const unsigned short* p = wpc + (((size_t)ftb * KC + kc) * 2) * 512 + (size_t)l * 8;
            whi[ch * 4 + j] = *reinterpret_cast<const bf16x8*>(p);
            wlo[ch * 4 + j] = *reinterpret_cast<const bf16x8*>(p + 512);
        }
    }

    // ---- per-thread recurrent state ----
    const int u_l = w, b = l;
    const int ug = ftb * 4 + u_l;
    const size_t sidx = ((size_t)cell * BATCH + b) * HSZ + ug;
    float h_reg = h0[sidx];
    float c_reg = c0[sidx];
    const float* bih = cd ? bihb : bihf;
    const float* bhh = cd ? bhhb : bhhf;
    float bsum[4];
#pragma unroll
    for (int g = 0; g < 4; ++g) bsum[g] = bih[g * 512 + ug] + bhh[g * 512 + ug];
    const int len = lengths[b];

    for (int s = 0; s < T_LEN; ++s) {
        const int t = cd ? (T_LEN - 1 - s) : s;
        const unsigned short* hrdHi = (s & 1) ? hhi1 : hhi0;
        const unsigned short* hrdLo = (s & 1) ? hlo1 : hlo0;
        unsigned short* hwrHi = (s & 1) ? hhi0 : hhi1;
        unsigned short* hwrLo = (s & 1) ? hlo0 : hlo1;

        f32x4 acc[4] = {};

#pragma unroll
        for (int ch = 0; ch < NCH; ++ch) {
            // ---- stage chunk ch (64 batches x 512 k, split bf16) ----
            if (ch == NCH - 1) {
                // h-state chunk: pure copy of pre-split state
                const unsigned short* sh = hrdHi + (size_t)cell * BATCH * HSZ;
                const unsigned short* sl = hrdLo + (size_t)cell * BATCH * HSZ;
#pragma unroll
                for (int i = 0; i < 16; ++i) {
                    int f = i * 256 + tid, row = f >> 6, q = f & 63;
                    *reinterpret_cast<uint4*>(&sm.z.hi[row][q * 8]) =
                        *reinterpret_cast<const uint4*>(&sh[(size_t)row * 512 + q * 8]);
                    *reinterpret_cast<uint4*>(&sm.z.lo[row][q * 8]) =
                        *reinterpret_cast<const uint4*>(&sl[(size_t)row * 512 + q * 8]);
                }
            } else {
                if constexpr (DIN == 512) {
                    // x chunk: fp32 -> split on the fly
                    const float* src = zf32 + ((size_t)t * BATCH) * 512;
#pragma unroll
                    for (int i = 0; i < 32; ++i) {
                        int f = i * 256 + tid, row = f >> 7, q = f & 127;
                        float4 v = *reinterpret_cast<const float4*>(&src[(size_t)row * 512 + q * 4]);
                        unsigned short H[4], L[4];
                        split2(v.x, H[0], L[0]); split2(v.y, H[1], L[1]);
                        split2(v.z, H[2], L[2]); split2(v.w, H[3], L[3]);
                        ushort4 Hv = { H[0], H[1], H[2], H[3] };
                        ushort4 Lv = { L[0], L[1], L[2], L[3] };
                        *reinterpret_cast<ushort4*>(&sm.z.hi[row][q * 4]) = Hv;
                        *reinterpret_cast<ushort4*>(&sm.z.lo[row][q * 4]) = Lv;
                    }
                } else {
                    // h1 chunk: pure copy of pre-split h1
                    const unsigned short* sh = zsh + ((size_t)t * BATCH) * 1024 + ch * 512;
                    const unsigned short* sl = zsl + ((size_t)t * BATCH) * 1024 + ch * 512;
#pragma unroll
                    for (int i = 0; i < 16; ++i) {
                        int f = i * 256 + tid, row = f >> 6, q = f & 63;
                        *reinterpret_cast<uint4*>(&sm.z.hi[row][q * 8]) =
                            *reinterpret_cast<const uint4*>(&sh[(size_t)row * 1024 + q * 8]);
                        *reinterpret_cast<uint4*>(&sm.z.lo[row][q * 8]) =
                            *reinterpret_cast<const uint4*>(&sl[(size_t)row * 1024 + q * 8]);
                    }
                }
            }
            __syncthreads();

            // ---- MFMA over chunk: wave w covers kc_local in [w*4, w*4+4) ----
#pragma unroll
            for (int j = 0; j < 4; ++j) {
                const int koff = (w * 4 + j) * 32 + (l >> 4) * 8;
#pragma unroll
                for (int nt = 0; nt < 4; ++nt) {
                    const int r = nt * 16 + (l & 15);
                    bf16x8 bhi = *reinterpret_cast<const bf16x8*>(&sm.z.hi[r][koff]);
                    bf16x8 blo = *reinterpret_cast<const bf16x8*>(&sm.z.lo[r][koff]);
                    acc[nt] = __builtin_amdgcn_mfma_f32_16x16x32_bf16(whi[ch * 4 + j], bhi, acc[nt], 0, 0, 0);
                    acc[nt] = __builtin_amdgcn_mfma_f32_16x16x32_bf16(whi[ch * 4 + j], blo, acc[nt], 0, 0, 0);
                    acc[nt] = __builtin_amdgcn_mfma_f32_16x16x32_bf16(wlo[ch * 4 + j], bhi, acc[nt], 0, 0, 0);
                }
            }
            __syncthreads();
        }

        // ---- cross-wave partial reduction via LDS ----
#pragma unroll
        for (int nt = 0; nt < 4; ++nt) {
#pragma unroll
            for (int r = 0; r < 4; ++r) {
                sm.part[w][nt][(l >> 4) * 4 + r][l & 15] = acc[nt][r];
            }
        }
        __syncthreads();

        // ---- epilogue: this thread owns (u_l, b) ----
        {
            const int nt = b >> 4, col = b & 15;
            float pre[4];
#pragma unroll
            for (int g = 0; g < 4; ++g) {
                float ssum = 0.f;
#pragma unroll
                for (int ww = 0; ww < 4; ++ww) ssum += sm.part[ww][nt][u_l * 4 + g][col];
                pre[g] = ssum + bsum[g];
            }
            const float gi = sigmoid_fast(pre[0]);
            const float gf = sigmoid_fast(pre[1]);
            const float gg = tanh_fast(pre[2]);
            const float go = sigmoid_fast(pre[3]);
            const float cy = gf * c_reg + gi * gg;
            const float hy = go * tanh_fast(cy);
            const bool m = (t < len);
            if (m) { c_reg = cy; h_reg = hy; }
            unsigned short hh, hl;
            split2(h_reg, hh, hl);
            hwrHi[sidx] = hh; hwrLo[sidx] = hl;
            const float ov = m ? hy : 0.f;
            if constexpr (DIN == 512) {
                unsigned short oh, ol;
                split2(ov, oh, ol);
                size_t oidx = ((size_t)t * BATCH + b) * 1024 + (size_t)cd * 512 + ug;
                oshi[oidx] = oh; oslo[oidx] = ol;
            } else {
                of32[((size_t)t * BATCH + b) * 1024 + (size_t)cd * 512 + ug] = ov;
            }
        }

        barrier2(cgrp, croot, cgen, gidx, 32, 4);
    }
}

// ---------- the persistent kernel: both layers, all 512 steps ----------
__global__ __launch_bounds__(256, 1)
void lstm_persistent(const float* __restrict__ x, const int* __restrict__ lengths,
                     const unsigned short* __restrict__ wp_l0, const unsigned short* __restrict__ wp_l1,
                     const float* __restrict__ bih0f, const float* __restrict__ bhh0f,
                     const float* __restrict__ bih0b, const float* __restrict__ bhh0b,
                     const float* __restrict__ bih1f, const float* __restrict__ bhh1f,
                     const float* __restrict__ bih1b, const float* __restrict__ bhh1b,
                     const float* __restrict__ h0, const float* __restrict__ c0,
                     unsigned short* __restrict__ hhi0, unsigned short* __restrict__ hlo0,
                     unsigned short* __restrict__ hhi1, unsigned short* __restrict__ hlo1,
                     unsigned short* __restrict__ h1hi, unsigned short* __restrict__ h1lo,
                     float* __restrict__ out, unsigned* bar)
{
    __shared__ Shm sm;

    // phase 0: layer 0 (cells 0,1), input x, output h1 (split)
    run_phase<512>(sm, x, nullptr, nullptr, wp_l0,
                   bih0f, bhh0f, bih0b, bhh0b, h0, c0,
                   hhi0, hlo0, hhi1, hlo1,
                   h1hi, h1lo, nullptr, lengths, bar, 0);

    // full-grid barrier: all h1 writes visible before layer 1 reads
    barrier2(bar + 192, bar + 320, bar + 336, blockIdx.x >> 5, 32, 8);

    // phase 1: layer 1 (cells 2,3), input h1 (split), output d_out (fp32)
    run_phase<1024>(sm, nullptr, h1hi, h1lo, wp_l1,
                    bih1f, bhh1f, bih1b, bhh1b, h0, c0,
                    hhi0, hlo0, hhi1, hlo1,
                    nullptr, nullptr, out, lengths, bar, 2);
}

extern "C" void kernel_launch(void* const* d_in, const int* in_sizes, int n_in,
                              void* d_out, int out_size, void* d_ws, size_t ws_size,
                              hipStream_t stream) {
    const float* x        = (const float*)d_in[0];
    const int*   lengths  = (const int*)d_in[1];
    const float* h0       = (const float*)d_in[2];
    const float* c0       = (const float*)d_in[3];
    const float* w_ih_l0  = (const float*)d_in[4];
    const float* w_hh_l0  = (const float*)d_in[5];
    const float* b_ih_l0  = (const float*)d_in[6];
    const float* b_hh_l0  = (const float*)d_in[7];
    const float* w_ih_l0r = (const float*)d_in[8];
    const float* w_hh_l0r = (const float*)d_in[9];
    const float* b_ih_l0r = (const float*)d_in[10];
    const float* b_hh_l0r = (const float*)d_in[11];
    const float* w_ih_l1  = (const float*)d_in[12];
    const float* w_hh_l1  = (const float*)d_in[13];
    const float* b_ih_l1  = (const float*)d_in[14];
    const float* b_hh_l1  = (const float*)d_in[15];
    const float* w_ih_l1r = (const float*)d_in[16];
    const float* w_hh_l1r = (const float*)d_in[17];
    const float* b_ih_l1r = (const float*)d_in[18];
    const float* b_hh_l1r = (const float*)d_in[19];

    float* out = (float*)d_out;

    // ---- ws carve-up ----
    unsigned* bar = (unsigned*)d_ws;                               // 2048 B of counters
    unsigned short* p = (unsigned short*)((char*)d_ws + 2048);
    unsigned short* hhi0 = p; p += (size_t)4 * BATCH * HSZ;        // 131072 each
    unsigned short* hlo0 = p; p += (size_t)4 * BATCH * HSZ;
    unsigned short* hhi1 = p; p += (size_t)4 * BATCH * HSZ;
    unsigned short* hlo1 = p; p += (size_t)4 * BATCH * HSZ;
    unsigned short* h1hi = p; p += (size_t)T_LEN * BATCH * 1024;   // 16,777,216 each
    unsigned short* h1lo = p; p += (size_t)T_LEN * BATCH * 1024;
    unsigned short* wp_l0 = p; p += (size_t)2 * 128 * 32 * 2 * 512; // 8,388,608
    unsigned short* wp_l1 = p;                                      // 12,582,912

    hipMemsetAsync(bar, 0, 2048, stream);

    hipLaunchKernelGGL(init_split, dim3(512), dim3(256), 0, stream, h0, hhi0, hlo0);

    hipLaunchKernelGGL((pack_weights<512>),  dim3(2048), dim3(256), 0, stream,
                       w_ih_l0, w_hh_l0, w_ih_l0r, w_hh_l0r, wp_l0);
    hipLaunchKernelGGL((pack_weights<1024>), dim3(3072), dim3(256), 0, stream,
                       w_ih_l1, w_hh_l1, w_ih_l1r, w_hh_l1r, wp_l1);

    hipLaunchKernelGGL(lstm_persistent, dim3(256), dim3(256), 0, stream,
                       x, lengths, wp_l0, wp_l1,
                       b_ih_l0, b_hh_l0, b_ih_l0r, b_hh_l0r,
                       b_ih_l1, b_hh_l1, b_ih_l1r, b_hh_l1r,
                       h0, c0,
                       hhi0, hlo0, hhi1, hlo1, h1hi, h1lo,
                       out, bar);
}

// Round 4
// 9614.590 us; speedup vs baseline: 2.7446x; 2.7446x over previous
//
#include <hip/hip_runtime.h>
#include <hip/hip_bf16.h>
#include <math.h>

// Problem constants: T=256, B=64, I=512, H=512
#define T_LEN 256
#define BATCH 64
#define HSZ   512

typedef __bf16 bf16x8 __attribute__((ext_vector_type(8)));
typedef float  f32x4  __attribute__((ext_vector_type(4)));

// ---------- bf16 split helpers ----------
__device__ __forceinline__ unsigned short f2bf_rne(float f) {
    union { float f; unsigned int u; } c; c.f = f;
    unsigned int u = c.u;
    unsigned int r = (u + 0x7fffu + ((u >> 16) & 1u)) >> 16;
    return (unsigned short)r;
}
__device__ __forceinline__ float bf2f(unsigned short h) {
    union { unsigned int u; float f; } c; c.u = ((unsigned int)h) << 16;
    return c.f;
}
__device__ __forceinline__ void split_rne(float v, unsigned short& hi, unsigned short& lo) {
    hi = f2bf_rne(v);
    lo = f2bf_rne(v - bf2f(hi));
}
// fast truncating split (4 VALU). |err| <= 2^-16 |v|
__device__ __forceinline__ void split2(float v, unsigned short& hi, unsigned short& lo) {
    unsigned int u = __float_as_uint(v);
    hi = (unsigned short)(u >> 16);
    float rem = v - __uint_as_float(u & 0xffff0000u);
    lo = (unsigned short)(__float_as_uint(rem) >> 16);
}

__device__ __forceinline__ float sigmoid_fast(float x) {
    return 1.0f / (1.0f + __expf(-x));
}
__device__ __forceinline__ float tanh_fast(float x) {
    float e = __expf(2.0f * x);
    return 1.0f - 2.0f / (e + 1.0f);
}

// ============================================================================
// B-fragment layouts (ushort):
//   xf  [t][nt(4)][kc(16)][pl(2)][lane(64)][e(8)]   (x, K=512)       33.5 MB
//   h1f [t][nt(4)][kc(32)][pl(2)][lane(64)][e(8)]   (h1, K=1024)     67 MB
//   st  [par(2)][cell(4)][nt(4)][kc(16)][pl(2)][lane(64)][e(8)]      1 MB
// B-frag semantics (16x16x32): lane l holds B[col = nt*16 + (l&15)]
//                                       [k  = kc*32 + (l>>4)*8 + e]
// A-frag (weights) wp[cell(2)][bu(64)][strip(2)][kc(KC)][pl(2)][lane][e]:
//   lane l holds A[pr_g = bu*32 + strip*16 + (l&15)][k = kc*32 + (l>>4)*8 + e]
//   pr_g = unit*4 + gate  (gate-interleaved rows)
// ============================================================================

// ---------- pack x into B-frag hi/lo layout ----------
__global__ __launch_bounds__(256)
void pack_x(const float* __restrict__ x, unsigned short* __restrict__ xf) {
    int t = blockIdx.x * 256 + threadIdx.x;       // 4096*256 = 256*4*16*64
    int lane = t & 63;
    int id = t >> 6;
    int kc = id & 15; id >>= 4;
    int nt = id & 3;  id >>= 2;
    int tt = id;                                   // 0..255
    int b  = nt * 16 + (lane & 15);
    int k0 = kc * 32 + (lane >> 4) * 8;
    const float* src = x + ((size_t)tt * BATCH + b) * 512 + k0;
    union { unsigned short s[8]; uint4 v; } H, L;
#pragma unroll
    for (int e = 0; e < 8; ++e) split_rne(src[e], H.s[e], L.s[e]);
    size_t base = ((((size_t)tt * 4 + nt) * 16 + kc) * 2) * 512 + (size_t)lane * 8;
    *reinterpret_cast<uint4*>(&xf[base])       = H.v;
    *reinterpret_cast<uint4*>(&xf[base + 512]) = L.v;
}

// ---------- pack weights into per-block A-frag layout ----------
template<int KC>   // 32 (L0) or 48 (L1);  DIN = (KC-16)*32
__global__ __launch_bounds__(256)
void pack_w(const float* __restrict__ wih0, const float* __restrict__ whh0,
            const float* __restrict__ wih1, const float* __restrict__ whh1,
            unsigned short* __restrict__ wp) {
    constexpr int DIN = (KC - 16) * 32;
    int t = blockIdx.x * 256 + threadIdx.x;        // 2*64*2*KC*64 threads
    int lane = t & 63;
    int id = t >> 6;
    int kc = id % KC; id /= KC;
    int strip = id & 1; id >>= 1;
    int bu = id & 63; id >>= 6;
    int cell = id;
    if (cell >= 2) return;
    const float* wih = cell ? wih1 : wih0;
    const float* whh = cell ? whh1 : whh0;
    int pr_g = bu * 32 + strip * 16 + (lane & 15);
    int u_g = pr_g >> 2, g = pr_g & 3;
    int row = g * 512 + u_g;
    int k0 = kc * 32 + (lane >> 4) * 8;
    union { unsigned short s[8]; uint4 v; } H, L;
#pragma unroll
    for (int e = 0; e < 8; ++e) {
        int k = k0 + e;
        float v = (k < DIN) ? wih[(size_t)row * DIN + k]
                            : whh[(size_t)row * 512 + (k - DIN)];
        split_rne(v, H.s[e], L.s[e]);
    }
    size_t base = (((((size_t)cell * 64 + bu) * 2 + strip) * KC + kc) * 2) * 512 + (size_t)lane * 8;
    *reinterpret_cast<uint4*>(&wp[base])       = H.v;
    *reinterpret_cast<uint4*>(&wp[base + 512]) = L.v;
}

// ---------- init h-state (parity 0) in frag layout ----------
__global__ __launch_bounds__(256)
void init_state(const float* __restrict__ h0, unsigned short* __restrict__ st) {
    int i = blockIdx.x * 256 + threadIdx.x;       // 4*64*512
    int cell = i >> 15;
    int r = i & 32767;
    int b = r >> 9;
    int u = r & 511;
    unsigned short hh, hl;
    split_rne(h0[((size_t)cell * BATCH + b) * 512 + u], hh, hl);
    int nt = b >> 4, kc = u >> 5, rr = u & 31;
    int lane = ((rr >> 3) << 4) | (b & 15);
    int e = rr & 7;
    size_t sb = (((((size_t)0 * 4 + cell) * 4 + nt) * 16 + kc) * 2) * 512 + (size_t)lane * 8 + e;
    st[sb] = hh;
    st[sb + 512] = hl;
}

// ---------- one layer phase: 256 steps, both directions ----------
// Grid: 128 blocks = cd(1bit) x bu(64). Block owns 32 gate-rows (8 units) x 64 batches.
// Wave w owns kc in {w, w+4, w+8, ...}: x-kcs first (no dependency), then spin, then h-kcs.
template<int DIN>
__global__ __launch_bounds__(256, 1)
void lstm_phase(const unsigned short* __restrict__ bfr,   // xf (L0) or h1f (L1)
                const unsigned short* __restrict__ wp,
                const float* __restrict__ bihf, const float* __restrict__ bhhf,
                const float* __restrict__ bihb, const float* __restrict__ bhhb,
                const float* __restrict__ h0, const float* __restrict__ c0,
                const int* __restrict__ lengths,
                unsigned short* __restrict__ st,
                unsigned short* __restrict__ h1f,         // written by L0
                float* __restrict__ out,                  // written by L1
                unsigned* __restrict__ bar,               // this phase's 2-dir region
                int cellbase)
{
    constexpr int KC   = (DIN + 512) / 32;   // 32 or 48
    constexpr int KCW  = KC / 4;             // 8 or 12 kc per wave
    constexpr int XCW  = DIN / 128;          // x-kc per wave: 4 or 8
    constexpr int NXKC = DIN / 32;           // 16 or 32
    constexpr size_t TBLK = (size_t)4 * NXKC * 2 * 512;   // per-t input block

    const int bx = blockIdx.x;
    const int cd = bx & 1;
    const int bu = bx >> 1;
    const int cell = cellbase + cd;
    const int tid = threadIdx.x;
    const int w = tid >> 6, l = tid & 63;

    __shared__ float part[4][2][4][16][17];   // [wave][strip][nt][row][col(+pad)]

    unsigned* grp  = bar + (size_t)cd * 256;  // grp[8] at 0,16,..,112; root 128; gen 144
    unsigned* root = grp + 128;
    unsigned* gen  = grp + 144;
    const int gidx = bu >> 3;

    // ---- persistent weights in registers ----
    bf16x8 wreg[2][KCW][2];
#pragma unroll
    for (int m = 0; m < 2; ++m) {
#pragma unroll
        for (int i = 0; i < KCW; ++i) {
            int kc = w + 4 * i;
            const unsigned short* p = wp +
                (((((size_t)cd * 64 + bu) * 2 + m) * KC + kc) * 2) * 512 + (size_t)l * 8;
            wreg[m][i][0] = *reinterpret_cast<const bf16x8*>(p);
            wreg[m][i][1] = *reinterpret_cast<const bf16x8*>(p + 512);
        }
    }

    // ---- per-thread recurrent state: units {w, w+4} for batch b_t ----
    const int b_t = tid & 63;
    const int len = lengths[b_t];
    const float* bih = cd ? bihb : bihf;
    const float* bhh = cd ? bhhb : bhhf;
    float h_reg[2], c_reg[2], bsum[2][4];
#pragma unroll
    for (int ui = 0; ui < 2; ++ui) {
        int u_g = bu * 8 + w + 4 * ui;
        size_t sidx = ((size_t)cell * BATCH + b_t) * HSZ + u_g;
        h_reg[ui] = h0[sidx];
        c_reg[ui] = c0[sidx];
#pragma unroll
        for (int g = 0; g < 4; ++g)
            bsum[ui][g] = bih[g * 512 + u_g] + bhh[g * 512 + u_g];
    }

    const unsigned short* stc = st;   // [par][cell][nt][kc16][pl][l][e]

    for (int s = 0; s < T_LEN; ++s) {
        const int t = cd ? (T_LEN - 1 - s) : s;
        f32x4 acc[2][4] = {};

        // ---- x-part (no cross-block dependency) ----
        const unsigned short* bt = bfr + (size_t)t * TBLK;
#pragma unroll
        for (int i = 0; i < XCW; ++i) {
            int kc = w + 4 * i;
#pragma unroll
            for (int nt = 0; nt < 4; ++nt) {
                const unsigned short* p = bt + (((size_t)nt * NXKC + kc) * 2) * 512 + (size_t)l * 8;
                bf16x8 bhi = *reinterpret_cast<const bf16x8*>(p);
                bf16x8 blo = *reinterpret_cast<const bf16x8*>(p + 512);
#pragma unroll
                for (int m = 0; m < 2; ++m) {
                    acc[m][nt] = __builtin_amdgcn_mfma_f32_16x16x32_bf16(wreg[m][i][0], bhi, acc[m][nt], 0, 0, 0);
                    acc[m][nt] = __builtin_amdgcn_mfma_f32_16x16x32_bf16(wreg[m][i][0], blo, acc[m][nt], 0, 0, 0);
                    acc[m][nt] = __builtin_amdgcn_mfma_f32_16x16x32_bf16(wreg[m][i][1], bhi, acc[m][nt], 0, 0, 0);
                }
            }
        }

        // ---- wait for h-state of step s ----
        while (__hip_atomic_load(gen, __ATOMIC_ACQUIRE, __HIP_MEMORY_SCOPE_AGENT) < (unsigned)s)
            __builtin_amdgcn_s_sleep(4);

        // ---- h-part ----
        const unsigned short* hb = stc + ((size_t)(s & 1) * 4 + cell) * 65536;
#pragma unroll
        for (int i = XCW; i < KCW; ++i) {
            int kch = w + 4 * i - NXKC;   // 0..15
#pragma unroll
            for (int nt = 0; nt < 4; ++nt) {
                const unsigned short* p = hb + (((size_t)nt * 16 + kch) * 2) * 512 + (size_t)l * 8;
                bf16x8 bhi = *reinterpret_cast<const bf16x8*>(p);
                bf16x8 blo = *reinterpret_cast<const bf16x8*>(p + 512);
#pragma unroll
                for (int m = 0; m < 2; ++m) {
                    acc[m][nt] = __builtin_amdgcn_mfma_f32_16x16x32_bf16(wreg[m][i][0], bhi, acc[m][nt], 0, 0, 0);
                    acc[m][nt] = __builtin_amdgcn_mfma_f32_16x16x32_bf16(wreg[m][i][0], blo, acc[m][nt], 0, 0, 0);
                    acc[m][nt] = __builtin_amdgcn_mfma_f32_16x16x32_bf16(wreg[m][i][1], bhi, acc[m][nt], 0, 0, 0);
                }
            }
        }

        // ---- cross-wave partials ----
#pragma unroll
        for (int m = 0; m < 2; ++m)
#pragma unroll
            for (int nt = 0; nt < 4; ++nt)
#pragma unroll
                for (int j = 0; j < 4; ++j)
                    part[w][m][nt][(l >> 4) * 4 + j][l & 15] = acc[m][nt][j];
        __syncthreads();

        // ---- epilogue: thread owns (units {w, w+4}, batch b_t) ----
#pragma unroll
        for (int ui = 0; ui < 2; ++ui) {
            const int uu = w + 4 * ui;           // unit-in-block 0..7
            const int u_g = bu * 8 + uu;
            float pre[4];
#pragma unroll
            for (int g = 0; g < 4; ++g) {
                int pr = uu * 4 + g;
                int m = pr >> 4, row = pr & 15;
                float ssum = 0.f;
#pragma unroll
                for (int ww = 0; ww < 4; ++ww)
                    ssum += part[ww][m][b_t >> 4][row][b_t & 15];
                pre[g] = ssum + bsum[ui][g];
            }
            const float gi = sigmoid_fast(pre[0]);
            const float gf = sigmoid_fast(pre[1]);
            const float gg = tanh_fast(pre[2]);
            const float go = sigmoid_fast(pre[3]);
            const float cy = gf * c_reg[ui] + gi * gg;
            const float hy = go * tanh_fast(cy);
            const bool mM = (t < len);
            if (mM) { c_reg[ui] = cy; h_reg[ui] = hy; }

            // state write (parity (s+1)&1), frag layout
            unsigned short hh, hl;
            split2(h_reg[ui], hh, hl);
            {
                int kcs = u_g >> 5, rr = u_g & 31;
                int lane_t = ((rr >> 3) << 4) | (b_t & 15);
                int ee = rr & 7;
                size_t sb = (((((size_t)((s + 1) & 1) * 4 + cell) * 4 + (b_t >> 4)) * 16 + kcs) * 2) * 512
                          + (size_t)lane_t * 8 + ee;
                st[sb] = hh;
                st[sb + 512] = hl;
            }
            const float ov = mM ? hy : 0.f;
            if constexpr (DIN == 512) {
                unsigned short oh, ol;
                split2(ov, oh, ol);
                int k1 = cd * 512 + u_g;
                int kc1 = k1 >> 5, r1 = k1 & 31;
                int lane1 = ((r1 >> 3) << 4) | (b_t & 15);
                int e1 = r1 & 7;
                size_t ob = ((((size_t)t * 4 + (b_t >> 4)) * 32 + kc1) * 2) * 512 + (size_t)lane1 * 8 + e1;
                h1f[ob] = oh;
                h1f[ob + 512] = ol;
            } else {
                out[((size_t)t * BATCH + b_t) * 1024 + cd * 512 + u_g] = ov;
            }
        }
        __syncthreads();

        // ---- arrive (two-level 8x8) ----
        if (tid == 0) {
            unsigned a = __hip_atomic_fetch_add(grp + (size_t)gidx * 16, 1u,
                                                __ATOMIC_ACQ_REL, __HIP_MEMORY_SCOPE_AGENT);
            if (a == 7u) {
                unsigned r = __hip_atomic_fetch_add(root, 1u,
                                                    __ATOMIC_ACQ_REL, __HIP_MEMORY_SCOPE_AGENT);
                if (r == 7u) {
                    for (int i = 0; i < 8; ++i)
                        __hip_atomic_store(grp + (size_t)i * 16, 0u, __ATOMIC_RELAXED, __HIP_MEMORY_SCOPE_AGENT);
                    __hip_atomic_store(root, 0u, __ATOMIC_RELAXED, __HIP_MEMORY_SCOPE_AGENT);
                    __hip_atomic_fetch_add(gen, 1u, __ATOMIC_RELEASE, __HIP_MEMORY_SCOPE_AGENT);
                }
            }
        }
    }
}

extern "C" void kernel_launch(void* const* d_in, const int* in_sizes, int n_in,
                              void* d_out, int out_size, void* d_ws, size_t ws_size,
                              hipStream_t stream) {
    const float* x        = (const float*)d_in[0];
    const int*   lengths  = (const int*)d_in[1];
    const float* h0       = (const float*)d_in[2];
    const float* c0       = (const float*)d_in[3];
    const float* w_ih_l0  = (const float*)d_in[4];
    const float* w_hh_l0  = (const float*)d_in[5];
    const float* b_ih_l0  = (const float*)d_in[6];
    const float* b_hh_l0  = (const float*)d_in[7];
    const float* w_ih_l0r = (const float*)d_in[8];
    const float* w_hh_l0r = (const float*)d_in[9];
    const float* b_ih_l0r = (const float*)d_in[10];
    const float* b_hh_l0r = (const float*)d_in[11];
    const float* w_ih_l1  = (const float*)d_in[12];
    const float* w_hh_l1  = (const float*)d_in[13];
    const float* b_ih_l1  = (const float*)d_in[14];
    const float* b_hh_l1  = (const float*)d_in[15];
    const float* w_ih_l1r = (const float*)d_in[16];
    const float* w_hh_l1r = (const float*)d_in[17];
    const float* b_ih_l1r = (const float*)d_in[18];
    const float* b_hh_l1r = (const float*)d_in[19];

    float* out = (float*)d_out;

    // ---- ws carve-up (bytes) ----
    char* base = (char*)d_ws;
    unsigned* bar = (unsigned*)base;                                   // 4096 B (2 phases x 2 dirs x 1KB)
    unsigned short* st  = (unsigned short*)(base + 4096);              // 1,048,576 B
    unsigned short* xf  = (unsigned short*)(base + 4096 + 1048576);    // 33,554,432 B
    unsigned short* h1f = (unsigned short*)(base + 4096 + 1048576 + 33554432);            // 67,108,864 B
    unsigned short* wp0 = (unsigned short*)(base + 4096 + 1048576 + 33554432 + 67108864); // 16,777,216 B
    unsigned short* wp1 = (unsigned short*)(base + 4096 + 1048576 + 33554432 + 67108864 + 16777216); // 25,165,824 B

    hipMemsetAsync(bar, 0, 4096, stream);

    hipLaunchKernelGGL(init_state, dim3(512), dim3(256), 0, stream, h0, st);
    hipLaunchKernelGGL(pack_x, dim3(4096), dim3(256), 0, stream, x, xf);
    hipLaunchKernelGGL((pack_w<32>), dim3(2048), dim3(256), 0, stream,
                       w_ih_l0, w_hh_l0, w_ih_l0r, w_hh_l0r, wp0);
    hipLaunchKernelGGL((pack_w<48>), dim3(3072), dim3(256), 0, stream,
                       w_ih_l1, w_hh_l1, w_ih_l1r, w_hh_l1r, wp1);

    // layer 0: input xf, writes h1f (cells 0,1)
    hipLaunchKernelGGL((lstm_phase<512>), dim3(128), dim3(256), 0, stream,
                       xf, wp0,
                       b_ih_l0, b_hh_l0, b_ih_l0r, b_hh_l0r,
                       h0, c0, lengths, st, h1f, out, bar, 0);

    // layer 1: input h1f, writes out (cells 2,3)
    hipLaunchKernelGGL((lstm_phase<1024>), dim3(128), dim3(256), 0, stream,
                       h1f, wp1,
                       b_ih_l1, b_hh_l1, b_ih_l1r, b_hh_l1r,
                       h0, c0, lengths, st, h1f, out, bar + 512, 2);
}